// Round 1
// baseline (157.860 us; speedup 1.0000x reference)
//
#include <hip/hip_runtime.h>
#include <math.h>
#include <stdint.h>

// Problem constants (fixed by the reference):
//   z_e: (32, 64, 32, 32) fp32  -> N = 32768 rows of C = 64 (c-stride = 1024 floats)
//   embedding: (1024, 64) fp32
//   outputs flat: z_q_ste (2097152) | loss (1) | indices (32768, as float)
#define NUM_EMB 1024
#define DIM 64
#define LOSS_OFF 2097152
#define IDX_OFF 2097153

// Constant-address-space float: uniform-address loads compile to s_load
// (scalar cache -> SGPR). SGPR operands in v_fma are free of the vector-memory
// broadcast tax.
typedef __attribute__((address_space(4))) const float cfloat_t;

// numpy fp32 pairwise tail: fold 16 lanes -> scalar (8,4,2,1 XOR-fold).
// Bitwise-matches the verified summation of prior rounds.
__device__ __forceinline__ float np_fold16(float* y) {
#pragma unroll
    for (int j = 0; j < 8; ++j) y[j] = __fadd_rn(y[j], y[j + 8]);
#pragma unroll
    for (int j = 0; j < 4; ++j) y[j] = __fadd_rn(y[j], y[j + 4]);
    y[0] = __fadd_rn(y[0], y[2]);
    y[1] = __fadd_rn(y[1], y[3]);
    return __fadd_rn(y[0], y[1]);
}

// ---- Kernel 0: per-code |e_k|^2 (verified chain) + zero the loss slot.
// Runs before vq_fused on the same stream, so the plain store to
// out[LOSS_OFF] is ordered ahead of all atomics (replaces hipMemsetAsync:
// one fewer dispatch). 16 blocks x 64 thr spreads the latency-bound loads
// over 16 CUs instead of 4.
__global__ void vq_emb_norms(const float* __restrict__ emb,
                             float* __restrict__ norms,
                             float* __restrict__ out) {
    int k = blockIdx.x * blockDim.x + threadIdx.x;
    if (k == 0) out[LOSS_OFF] = 0.0f;
    if (k < NUM_EMB) {
        const float* e = emb + k * DIM;
        float y[16];
#pragma unroll
        for (int j = 0; j < 16; ++j) {
            float a = __fadd_rn(__fmul_rn(e[j],      e[j]),
                                __fmul_rn(e[j + 16], e[j + 16]));
            float b = __fadd_rn(__fmul_rn(e[j + 32], e[j + 32]),
                                __fmul_rn(e[j + 48], e[j + 48]));
            y[j] = __fadd_rn(a, b);
        }
        norms[k] = np_fold16(y);
    }
}

// ---- Fused kernel: distances + argmin + indices + STE + loss ----
// 256 blocks x 512 thr (8 waves), exactly 1 block/CU, single round.
// Block owns 128 rows: lane = row within each of TWO 64-row sets
// (z0[64], z1[64] pinned in VGPRs). Wave w scans codes [w*128,(w+1)*128)
// via s_load; 2 codes x 2 rows = 4 independent FMA chains per lane, and
// each SGPR codebook element feeds TWO fmas (halved scalar-cache traffic
// vs the 1-row version). __launch_bounds__(512,2): VGPR cap 256, so the
// 128 pinned z values CANNOT be spilled/sunk (the r4/round-0 pathology
// that showed VGPR_Count=44 and a 2.2x-fat VALU stream).
// Packed u64 key (f32bits(d)<<32 | k): u64-min == np.argmin (d>0 ->
// monotone bits; ties -> lowest k). All per-(row,code) arithmetic chains
// are bitwise-identical to the verified kernel.
__global__ __launch_bounds__(512, 2)
void vq_fused(const float* __restrict__ z_e,
              const float* __restrict__ emb,
              const float* __restrict__ norms,
              float* __restrict__ out) {
    __shared__ unsigned long long s_keys[8][128];
    __shared__ int   s_final[128];
    __shared__ float s_loss[2][8];

    const int tid  = threadIdx.x;
    const int lane = tid & 63;
    const int wave = __builtin_amdgcn_readfirstlane(tid >> 6);  // pin uniform

    const int n0  = blockIdx.x * 128;         // first row of this block
    const int b   = n0 >> 10;                 // batch (H*W = 1024 rows per b)
    const int hw0 = (n0 & 1023) + lane;       // row-set 0: h*32+w
    const long zb0 = (long)b * 65536 + hw0;   // z_e[b][c][hw] = zb + c*1024
    const long zb1 = zb0 + 64;                // row-set 1 is hw0+64

    // Load both rows (coalesced 256B per c per set; contiguous 512B pair).
    float z0[DIM], z1[DIM];
#pragma unroll
    for (int c = 0; c < DIM; ++c) z0[c] = z_e[zb0 + (long)c * 1024];
#pragma unroll
    for (int c = 0; c < DIM; ++c) z1[c] = z_e[zb1 + (long)c * 1024];

    // PIN z in VGPRs: empty asm is an identity with an opaque result, so the
    // loads can't be sunk into the code loop or rematerialized. With the
    // 256-VGPR cap there is no spill pressure either. Zero numerics change.
#pragma unroll
    for (int c = 0; c < DIM; ++c) asm volatile("" : "+v"(z0[c]));
#pragma unroll
    for (int c = 0; c < DIM; ++c) asm volatile("" : "+v"(z1[c]));

    // A = numpy-bitwise sum(z^2), per row (verified chain).
    float A0, A1;
    {
        float y[16];
#pragma unroll
        for (int j = 0; j < 16; ++j) {
            float a = __fadd_rn(__fmul_rn(z0[j],      z0[j]),
                                __fmul_rn(z0[j + 16], z0[j + 16]));
            float c2 = __fadd_rn(__fmul_rn(z0[j + 32], z0[j + 32]),
                                 __fmul_rn(z0[j + 48], z0[j + 48]));
            y[j] = __fadd_rn(a, c2);
        }
        A0 = np_fold16(y);
    }
    {
        float y[16];
#pragma unroll
        for (int j = 0; j < 16; ++j) {
            float a = __fadd_rn(__fmul_rn(z1[j],      z1[j]),
                                __fmul_rn(z1[j + 16], z1[j + 16]));
            float c2 = __fadd_rn(__fmul_rn(z1[j + 32], z1[j + 32]),
                                 __fmul_rn(z1[j + 48], z1[j + 48]));
            y[j] = __fadd_rn(a, c2);
        }
        A1 = np_fold16(y);
    }

    // Scalar-path views of the codebook + norms (uniform addresses).
    cfloat_t* E  = (cfloat_t*)(uintptr_t)emb;
    cfloat_t* Nr = (cfloat_t*)(uintptr_t)norms;

    unsigned long long best0 = ~0ull, best1 = ~0ull;
    const int kbase = wave * (NUM_EMB / 8);   // 128 codes per wave, ascending
    for (int kk = 0; kk < NUM_EMB / 8; kk += 2) {
        const int k0 = kbase + kk;
        cfloat_t* e0 = E + (size_t)k0 * DIM;
        // 4 independent serial ascending-c fmaf chains (2 rows x 2 codes);
        // each scalar codebook element a0/a1 feeds two fmas. Per-chain
        // rounding order is bitwise == the verified rounds.
        float dot00 = 0.f, dot01 = 0.f, dot10 = 0.f, dot11 = 0.f;
#pragma unroll
        for (int c = 0; c < DIM; ++c) {
            const float a0 = e0[c];
            const float a1 = e0[c + DIM];
            dot00 = __fmaf_rn(z0[c], a0, dot00);
            dot10 = __fmaf_rn(z1[c], a0, dot10);
            dot01 = __fmaf_rn(z0[c], a1, dot01);
            dot11 = __fmaf_rn(z1[c], a1, dot11);
        }
        // Reference rounding chain: d = fl(fl(A - 2*dot) + E_k)
        const float nr0 = Nr[k0];
        const float nr1 = Nr[k0 + 1];
        const float d00 = __fadd_rn(__fmaf_rn(-2.f, dot00, A0), nr0);
        const float d01 = __fadd_rn(__fmaf_rn(-2.f, dot01, A0), nr1);
        const float d10 = __fadd_rn(__fmaf_rn(-2.f, dot10, A1), nr0);
        const float d11 = __fadd_rn(__fmaf_rn(-2.f, dot11, A1), nr1);
        const unsigned long long key00 =
            ((unsigned long long)__float_as_uint(d00) << 32) | (unsigned)k0;
        const unsigned long long key01 =
            ((unsigned long long)__float_as_uint(d01) << 32) | (unsigned)(k0 + 1);
        const unsigned long long key10 =
            ((unsigned long long)__float_as_uint(d10) << 32) | (unsigned)k0;
        const unsigned long long key11 =
            ((unsigned long long)__float_as_uint(d11) << 32) | (unsigned)(k0 + 1);
        if (key00 < best0) best0 = key00;
        if (key01 < best0) best0 = key01;
        if (key10 < best1) best1 = key10;
        if (key11 < best1) best1 = key11;
    }
    s_keys[wave][lane]      = best0;
    s_keys[wave][64 + lane] = best1;
    __syncthreads();

    // Per-row u64 min over the 8 waves; write indices.
    if (tid < 128) {
        unsigned long long m = s_keys[0][tid];
#pragma unroll
        for (int w = 1; w < 8; ++w) {
            unsigned long long t = s_keys[w][tid];
            if (t < m) m = t;
        }
        const int k = (int)(m & 0xFFFFFFFFu);
        s_final[tid] = k;
        out[IDX_OFF + n0 + tid] = (float)k;   // indices compared as float
    }
    __syncthreads();

    // STE + loss: wave w handles c in [w*8, w*8+8) for all 128 rows
    // (lane = row keeps loads/stores coalesced). Per-element math and the
    // per-64-row-set partial-sum structure are bitwise == the verified
    // rounds (two 64-row partials -> two atomic contributions, exactly like
    // two of the old 64-row blocks).
    const int f0 = s_final[lane];
    const int f1 = s_final[64 + lane];
    float ls0 = 0.f, ls1 = 0.f;
#pragma unroll
    for (int j = 0; j < DIM / 8; ++j) {
        const int c = wave * 8 + j;
        const float zc0 = z_e[zb0 + (long)c * 1024];     // L1-hot
        const float ec0 = emb[f0 * DIM + c];             // per-lane gather, L2-hot
        out[((long)(b * 64 + c)) * 1024 + hw0] = zc0 + (ec0 - zc0);  // STE fwd
        const float dl0 = zc0 - ec0;
        ls0 = __fmaf_rn(dl0, dl0, ls0);
        const float zc1 = z_e[zb1 + (long)c * 1024];
        const float ec1 = emb[f1 * DIM + c];
        out[((long)(b * 64 + c)) * 1024 + hw0 + 64] = zc1 + (ec1 - zc1);
        const float dl1 = zc1 - ec1;
        ls1 = __fmaf_rn(dl1, dl1, ls1);
    }
#pragma unroll
    for (int off = 32; off >= 1; off >>= 1) {
        ls0 += __shfl_xor(ls0, off, 64);
        ls1 += __shfl_xor(ls1, off, 64);
    }
    if (lane == 0) { s_loss[0][wave] = ls0; s_loss[1][wave] = ls1; }
    __syncthreads();

    // TWO atomics per block (one per 64-row set): identical partial
    // grouping to the previous 512-block version.
    if (tid == 0) {
        float t0 = 0.f, t1 = 0.f;
#pragma unroll
        for (int w = 0; w < 8; ++w) t0 = __fadd_rn(t0, s_loss[0][w]);
#pragma unroll
        for (int w = 0; w < 8; ++w) t1 = __fadd_rn(t1, s_loss[1][w]);
        // 0.25 / 2097152 = 2^-23 exactly
        atomicAdd(out + LOSS_OFF, t0 * 1.1920928955078125e-07f);
        atomicAdd(out + LOSS_OFF, t1 * 1.1920928955078125e-07f);
    }
}

extern "C" void kernel_launch(void* const* d_in, const int* in_sizes, int n_in,
                              void* d_out, int out_size, void* d_ws, size_t ws_size,
                              hipStream_t stream) {
    const float* z_e = (const float*)d_in[0];
    const float* emb = (const float*)d_in[1];
    float* out   = (float*)d_out;
    float* norms = (float*)d_ws;   // 4 KB scratch

    // vq_emb_norms also zeroes out[LOSS_OFF] (stream-ordered before the
    // fused kernel's atomics) -> no separate memset dispatch.
    vq_emb_norms<<<dim3(16), dim3(64), 0, stream>>>(emb, norms, out);
    vq_fused<<<dim3(32768 / 128), dim3(512), 0, stream>>>(z_e, emb, norms, out);
}

// Round 3
// 148.220 us; speedup vs baseline: 1.0650x; 1.0650x over previous
//
#include <hip/hip_runtime.h>
#include <math.h>
#include <stdint.h>

// Problem constants (fixed by the reference):
//   z_e: (32, 64, 32, 32) fp32  -> N = 32768 rows of C = 64 (c-stride = 1024 floats)
//   embedding: (1024, 64) fp32
//   outputs flat: z_q_ste (2097152) | loss (1) | indices (32768, as float)
#define NUM_EMB 1024
#define DIM 64
#define LOSS_OFF 2097152
#define IDX_OFF 2097153
#define NROWS 32768
// Workspace needed for the split path: keys (2*32768*8 B) + norms (4 KB).
#define WS_KEYS_BYTES ((size_t)2 * NROWS * sizeof(unsigned long long))
#define WS_NEEDED (WS_KEYS_BYTES + NUM_EMB * sizeof(float))

// Constant-address-space float: uniform-address loads compile to s_load
// (scalar cache -> SGPR). SGPR operands in v_fma avoid the LDS/vector
// broadcast replication tax.
typedef __attribute__((address_space(4))) const float cfloat_t;

// numpy fp32 pairwise tail: fold 16 lanes -> scalar (8,4,2,1 XOR-fold).
// Bitwise-matches the verified summation of prior rounds.
__device__ __forceinline__ float np_fold16(float* y) {
#pragma unroll
    for (int j = 0; j < 8; ++j) y[j] = __fadd_rn(y[j], y[j + 8]);
#pragma unroll
    for (int j = 0; j < 4; ++j) y[j] = __fadd_rn(y[j], y[j + 4]);
    y[0] = __fadd_rn(y[0], y[2]);
    y[1] = __fadd_rn(y[1], y[3]);
    return __fadd_rn(y[0], y[1]);
}

// ---- Kernel 0: per-code |e_k|^2 (verified chain) + zero the loss slot.
// 16 pipelined float4 loads (one exposed DRAM round-trip) feeding the
// bitwise-verified summation chain.
__global__ void vq_emb_norms(const float* __restrict__ emb,
                             float* __restrict__ norms,
                             float* __restrict__ out) {
    int k = blockIdx.x * blockDim.x + threadIdx.x;
    if (k == 0) out[LOSS_OFF] = 0.0f;
    if (k < NUM_EMB) {
        const float4* e4 = reinterpret_cast<const float4*>(emb + k * DIM);
        float e2[DIM];
#pragma unroll
        for (int q = 0; q < 16; ++q) {
            const float4 v = e4[q];      // all 16 issued -> vmcnt-pipelined
            e2[q * 4 + 0] = v.x;
            e2[q * 4 + 1] = v.y;
            e2[q * 4 + 2] = v.z;
            e2[q * 4 + 3] = v.w;
        }
        float y[16];
#pragma unroll
        for (int j = 0; j < 16; ++j) {
            float a = __fadd_rn(__fmul_rn(e2[j],      e2[j]),
                                __fmul_rn(e2[j + 16], e2[j + 16]));
            float b = __fadd_rn(__fmul_rn(e2[j + 32], e2[j + 32]),
                                __fmul_rn(e2[j + 48], e2[j + 48]));
            y[j] = __fadd_rn(a, b);
        }
        norms[k] = np_fold16(y);
    }
}

// ---- Kernel 1 (split path): distance argmin over a code-half ----
// Grid 1024 = 512 row-groups x 2 code-halves; 512 thr (8 waves).
// Block owns 64 rows (lane = row, z[64] register-resident: arch VGPRs +
// unified-file AGPRs; VGPR_Count reports arch only). Wave w scans codes
// [h*512 + w*64, +64) via s_load, 2 codes in flight.
// __launch_bounds__(512,6): 6 waves/EU -> total-reg cap 85 (64 z + ~20
// misc fits) -> 3 blocks/CU resident vs round-0's 2. The hot loop is ~67%
// stalled on serial s_load round-trips (real VALU util ~33% after the
// gfx94x-formula 2x correction); +50% resident waves attacks exactly that.
// Packed u64 key (f32bits(d)<<32 | k): u64-min == np.argmin (d>0 ->
// monotone bits; ties -> lowest k). min is associative: this grouping
// picks the same winner as the verified single-kernel scan.
__global__ __launch_bounds__(512, 6)
void vq_argmin(const float* __restrict__ z_e,
               const float* __restrict__ emb,
               const float* __restrict__ norms,
               unsigned long long* __restrict__ keys) {
    __shared__ unsigned long long s_keys[8][64];

    const int tid  = threadIdx.x;
    const int lane = tid & 63;
    const int wave = __builtin_amdgcn_readfirstlane(tid >> 6);  // pin uniform

    const int rg = blockIdx.x >> 1;           // row-group (64 rows)
    const int h  = blockIdx.x & 1;            // code-half
    const int n0 = rg * 64;                   // first row of this group
    const int b  = n0 >> 10;                  // batch (H*W = 1024 rows per b)
    const int hw = (n0 & 1023) + lane;        // h*32 + w for this lane's row
    const long zbase = (long)b * 65536 + hw;  // z_e[b][c][hw] = zbase + c*1024

    // Load this lane's z row (coalesced 256B per c; waves 1..7 L1-hot).
    float z[DIM];
#pragma unroll
    for (int c = 0; c < DIM; ++c) z[c] = z_e[zbase + (long)c * 1024];

    // Keep z register-resident: empty asm is an identity with an opaque
    // result, so the loads can't be sunk into the code loop. Zero numerics
    // change -> correctness inherited from the verified rounds.
#pragma unroll
    for (int c = 0; c < DIM; ++c) asm volatile("" : "+v"(z[c]));

    // A = numpy-bitwise sum(z^2) (verified chain).
    float A;
    {
        float y[16];
#pragma unroll
        for (int j = 0; j < 16; ++j) {
            float a = __fadd_rn(__fmul_rn(z[j],      z[j]),
                                __fmul_rn(z[j + 16], z[j + 16]));
            float c2 = __fadd_rn(__fmul_rn(z[j + 32], z[j + 32]),
                                 __fmul_rn(z[j + 48], z[j + 48]));
            y[j] = __fadd_rn(a, c2);
        }
        A = np_fold16(y);
    }

    // Scalar-path views of the codebook + norms (uniform addresses).
    cfloat_t* E  = (cfloat_t*)(uintptr_t)emb;
    cfloat_t* Nr = (cfloat_t*)(uintptr_t)norms;

    unsigned long long best = ~0ull;
    const int kbase = h * 512 + wave * 64;    // 64 codes per wave, ascending
    for (int kk = 0; kk < 64; kk += 2) {
        const int k0 = kbase + kk;
        cfloat_t* e0 = E + (size_t)k0 * DIM;
        // Serial ascending-c fmaf chain per code (bitwise == verified);
        // two independent chains fill VALU issue within the stall gaps.
        float dot0 = 0.f, dot1 = 0.f;
#pragma unroll
        for (int c = 0; c < DIM; ++c) {
            dot0 = __fmaf_rn(z[c], e0[c], dot0);
            dot1 = __fmaf_rn(z[c], e0[c + DIM], dot1);
        }
        // Reference rounding chain: d = fl(fl(A - 2*dot) + E_k)
        const float d0 = __fadd_rn(__fmaf_rn(-2.f, dot0, A), Nr[k0]);
        const float d1 = __fadd_rn(__fmaf_rn(-2.f, dot1, A), Nr[k0 + 1]);
        const unsigned long long key0 =
            ((unsigned long long)__float_as_uint(d0) << 32) | (unsigned)k0;
        const unsigned long long key1 =
            ((unsigned long long)__float_as_uint(d1) << 32) | (unsigned)(k0 + 1);
        if (key0 < best) best = key0;
        if (key1 < best) best = key1;
    }
    s_keys[wave][lane] = best;
    __syncthreads();

    // Per-row u64 min over the 8 waves; one workspace slot per code-half
    // (written exactly once -> no init, no atomics; coalesced 512B store).
    if (tid < 64) {
        unsigned long long m = s_keys[0][tid];
#pragma unroll
        for (int w = 1; w < 8; ++w) {
            unsigned long long t = s_keys[w][tid];
            if (t < m) m = t;
        }
        keys[h * NROWS + n0 + tid] = m;
    }
}

// ---- Kernel 2 (split path): finalize — indices + STE + loss ----
// 512 blocks x 512 thr, block = 64 rows: EXACT round-0 epilogue structure
// (8 waves x 8-c slices, per-wave shfl reduce, 8 partials summed, ONE
// atomic per 64-row block) -> bitwise-identical loss/STE/indices to the
// verified kernel. Stream order guarantees keys are final.
__global__ __launch_bounds__(512, 4)
void vq_finalize(const float* __restrict__ z_e,
                 const float* __restrict__ emb,
                 const unsigned long long* __restrict__ keys,
                 float* __restrict__ out) {
    __shared__ int   s_final[64];
    __shared__ float s_loss[8];

    const int tid  = threadIdx.x;
    const int lane = tid & 63;
    const int wave = __builtin_amdgcn_readfirstlane(tid >> 6);

    const int n0 = blockIdx.x * 64;
    const int b  = n0 >> 10;
    const int hw = (n0 & 1023) + lane;
    const long zbase = (long)b * 65536 + hw;

    if (tid < 64) {
        unsigned long long m0 = keys[n0 + tid];
        unsigned long long m1 = keys[NROWS + n0 + tid];
        if (m1 < m0) m0 = m1;
        const int k = (int)(m0 & 0xFFFFFFFFu);
        s_final[tid] = k;
        out[IDX_OFF + n0 + tid] = (float)k;   // indices compared as float
    }
    __syncthreads();

    // STE + loss: wave w handles c in [w*8, w*8+8) for all 64 rows
    // (lane = row keeps loads/stores coalesced). Verified chain.
    const int fidx = s_final[lane];
    float lsum = 0.f;
#pragma unroll
    for (int j = 0; j < DIM / 8; ++j) {
        const int c = wave * 8 + j;
        const float zc = z_e[zbase + (long)c * 1024];   // L2-hot
        const float ec = emb[fidx * DIM + c];           // per-lane gather
        out[((long)(b * 64 + c)) * 1024 + hw] = zc + (ec - zc);  // STE forward
        const float dlt = zc - ec;
        lsum = __fmaf_rn(dlt, dlt, lsum);
    }
#pragma unroll
    for (int off = 32; off >= 1; off >>= 1) lsum += __shfl_xor(lsum, off, 64);
    if (lane == 0) s_loss[wave] = lsum;
    __syncthreads();

    // ONE atomic per 64-row block (identical grouping to round-0).
    if (tid == 0) {
        float t = 0.f;
#pragma unroll
        for (int w = 0; w < 8; ++w) t = __fadd_rn(t, s_loss[w]);
        // 0.25 / 2097152 = 2^-23 exactly
        atomicAdd(out + LOSS_OFF, t * 1.1920928955078125e-07f);
    }
}

// ---- Fallback (small workspace): the verified round-0 fused kernel ----
// Used only when ws_size can't hold the keys array. Needs just 4 KB
// (norms). Measured 91 us/dispatch; bitwise-verified numerics.
__global__ __launch_bounds__(512, 4)
void vq_fused(const float* __restrict__ z_e,
              const float* __restrict__ emb,
              const float* __restrict__ norms,
              float* __restrict__ out) {
    __shared__ unsigned long long s_keys[8 * 64];
    __shared__ int   s_final[64];
    __shared__ float s_loss[8];

    const int tid  = threadIdx.x;
    const int lane = tid & 63;
    const int wave = __builtin_amdgcn_readfirstlane(tid >> 6);

    const int n0 = blockIdx.x * 64;
    const int b  = n0 >> 10;
    const int hw = (n0 & 1023) + lane;
    const long zbase = (long)b * 65536 + hw;

    float z[DIM];
#pragma unroll
    for (int c = 0; c < DIM; ++c) z[c] = z_e[zbase + (long)c * 1024];
#pragma unroll
    for (int c = 0; c < DIM; ++c) asm volatile("" : "+v"(z[c]));

    float A;
    {
        float y[16];
#pragma unroll
        for (int j = 0; j < 16; ++j) {
            float a = __fadd_rn(__fmul_rn(z[j],      z[j]),
                                __fmul_rn(z[j + 16], z[j + 16]));
            float c2 = __fadd_rn(__fmul_rn(z[j + 32], z[j + 32]),
                                 __fmul_rn(z[j + 48], z[j + 48]));
            y[j] = __fadd_rn(a, c2);
        }
        A = np_fold16(y);
    }

    cfloat_t* E  = (cfloat_t*)(uintptr_t)emb;
    cfloat_t* Nr = (cfloat_t*)(uintptr_t)norms;

    unsigned long long best = ~0ull;
    const int kbase = wave * (NUM_EMB / 8);
    for (int kk = 0; kk < NUM_EMB / 8; kk += 2) {
        const int k0 = kbase + kk;
        cfloat_t* e0 = E + (size_t)k0 * DIM;
        cfloat_t* e1 = e0 + DIM;
        float dot0 = 0.f, dot1 = 0.f;
#pragma unroll
        for (int c = 0; c < DIM; ++c) {
            dot0 = __fmaf_rn(z[c], e0[c], dot0);
            dot1 = __fmaf_rn(z[c], e1[c], dot1);
        }
        const float d0 = __fadd_rn(__fmaf_rn(-2.f, dot0, A), Nr[k0]);
        const float d1 = __fadd_rn(__fmaf_rn(-2.f, dot1, A), Nr[k0 + 1]);
        const unsigned long long key0 =
            ((unsigned long long)__float_as_uint(d0) << 32) | (unsigned)k0;
        const unsigned long long key1 =
            ((unsigned long long)__float_as_uint(d1) << 32) | (unsigned)(k0 + 1);
        if (key0 < best) best = key0;
        if (key1 < best) best = key1;
    }
    s_keys[wave * 64 + lane] = best;
    __syncthreads();

    if (tid < 64) {
        unsigned long long m = s_keys[tid];
#pragma unroll
        for (int w = 1; w < 8; ++w) {
            unsigned long long t = s_keys[w * 64 + tid];
            if (t < m) m = t;
        }
        const int k = (int)(m & 0xFFFFFFFFu);
        s_final[tid] = k;
        out[IDX_OFF + n0 + tid] = (float)k;
    }
    __syncthreads();

    const int fidx = s_final[lane];
    float lsum = 0.f;
#pragma unroll
    for (int j = 0; j < DIM / 8; ++j) {
        const int c = wave * 8 + j;
        const float zc = z_e[zbase + (long)c * 1024];
        const float ec = emb[fidx * DIM + c];
        out[((long)(b * 64 + c)) * 1024 + hw] = zc + (ec - zc);
        const float dlt = zc - ec;
        lsum = __fmaf_rn(dlt, dlt, lsum);
    }
#pragma unroll
    for (int off = 32; off >= 1; off >>= 1) lsum += __shfl_xor(lsum, off, 64);
    if (lane == 0) s_loss[wave] = lsum;
    __syncthreads();

    if (tid == 0) {
        float t = 0.f;
#pragma unroll
        for (int w = 0; w < 8; ++w) t = __fadd_rn(t, s_loss[w]);
        atomicAdd(out + LOSS_OFF, t * 1.1920928955078125e-07f);
    }
}

extern "C" void kernel_launch(void* const* d_in, const int* in_sizes, int n_in,
                              void* d_out, int out_size, void* d_ws, size_t ws_size,
                              hipStream_t stream) {
    const float* z_e = (const float*)d_in[0];
    const float* emb = (const float*)d_in[1];
    float* out = (float*)d_out;

    if (ws_size >= WS_NEEDED) {
        // Split path: keys (512 KB) then norms (4 KB) in workspace.
        unsigned long long* keys = (unsigned long long*)d_ws;
        float* norms = (float*)((char*)d_ws + WS_KEYS_BYTES);
        vq_emb_norms<<<dim3(16), dim3(64), 0, stream>>>(emb, norms, out);
        vq_argmin<<<dim3(1024), dim3(512), 0, stream>>>(z_e, emb, norms, keys);
        vq_finalize<<<dim3(512), dim3(512), 0, stream>>>(z_e, emb, keys, out);
    } else {
        // Small workspace: verified single fused kernel (4 KB norms only).
        float* norms = (float*)d_ws;
        vq_emb_norms<<<dim3(16), dim3(64), 0, stream>>>(emb, norms, out);
        vq_fused<<<dim3(32768 / 64), dim3(512), 0, stream>>>(z_e, emb, norms, out);
    }
}